// Round 7
// baseline (737.916 us; speedup 1.0000x reference)
//
#include <hip/hip_runtime.h>
#include <stdint.h>

// BernoulliSampling: out[pos] = mean_{s<10}( U[s,pos] < sigmoid(z[pos]) )
// U = jax.random.uniform(key(42), (10, 8192, 4096)) via threefry-2x32,
// partitionable layout (JAX >= 0.5 default): bits(i) = o0^o1 of
// threefry(key=(0,42), x0 = i>>32 (=0 here, since 10*n < 2^32), x1 = i),
// flat i = s*n + pos.
// Comparison done exactly in integer domain: u < p  <=>  (bits>>9) < ceil(p*2^23).

#define NS 10u

__device__ __forceinline__ uint32_t rotl32(uint32_t x, uint32_t r) {
  return (x << r) | (x >> (32u - r));   // -> v_alignbit_b32
}

__device__ __forceinline__ void tf_round(uint32_t& x0, uint32_t& x1, uint32_t r) {
  x0 += x1;
  x1 = rotl32(x1, r);
  x1 ^= x0;
}

// threefry2x32 with key (k0=0, k1=42):
//   ks0=0, ks1=42, ks2=0x1BD11BDA^0^42=0x1BD11BF0
// Specialized for c0 == 0 (x0 starts at ks0 == 0).
__device__ __forceinline__ uint32_t threefry_0_42_fold(uint32_t c1) {
  uint32_t x0 = 0u;               // c0 + ks0
  uint32_t x1 = c1 + 42u;         // c1 + ks1
  tf_round(x0, x1, 13); tf_round(x0, x1, 15); tf_round(x0, x1, 26); tf_round(x0, x1, 6);
  x0 += 42u;           x1 += 0x1BD11BF0u + 1u;   // +ks1, +ks2+1
  tf_round(x0, x1, 17); tf_round(x0, x1, 29); tf_round(x0, x1, 16); tf_round(x0, x1, 24);
  x0 += 0x1BD11BF0u;   x1 += 0u + 2u;            // +ks2, +ks0+2
  tf_round(x0, x1, 13); tf_round(x0, x1, 15); tf_round(x0, x1, 26); tf_round(x0, x1, 6);
  x0 += 0u;            x1 += 42u + 3u;           // +ks0, +ks1+3
  tf_round(x0, x1, 17); tf_round(x0, x1, 29); tf_round(x0, x1, 16); tf_round(x0, x1, 24);
  x0 += 42u;           x1 += 0x1BD11BF0u + 4u;   // +ks1, +ks2+4
  tf_round(x0, x1, 13); tf_round(x0, x1, 15); tf_round(x0, x1, 26); tf_round(x0, x1, 6);
  x0 += 0x1BD11BF0u;   x1 += 0u + 5u;            // +ks2, +ks0+5
  return x0 ^ x1;                 // 32-bit partitionable fold
}

__global__ __launch_bounds__(256) void BernoulliSampling_kernel(
    const float* __restrict__ z, float* __restrict__ out, uint32_t n) {
  uint32_t pos = blockIdx.x * 256u + threadIdx.x;
  if (pos >= n) return;

  float zv = z[pos];
  // XLA LogisticExpander: sigmoid(x) = 1 / (1 + exp(-x)); expf == __ocml_exp_f32
  float p = 1.0f / (1.0f + expf(-zv));

  // u < p  <=>  (bits>>9) < ceil(p * 2^23)
  // (p*2^23 is an exact fp op: pow-2 scale of a [0,1] value; ceilf exact)
  uint32_t t = (uint32_t)ceilf(p * 8388608.0f);

  uint32_t cnt = 0;
#pragma unroll
  for (uint32_t s = 0; s < NS; ++s) {
    uint32_t bits = threefry_0_42_fold(s * n + pos);
    cnt += ((bits >> 9) < t) ? 1u : 0u;
  }

  out[pos] = (float)cnt * 0.1f;        // == cnt/10 within 1 ulp (<< tolerance)
}

extern "C" void kernel_launch(void* const* d_in, const int* in_sizes, int n_in,
                              void* d_out, int out_size, void* d_ws, size_t ws_size,
                              hipStream_t stream) {
  const float* z = (const float*)d_in[0];
  float* out = (float*)d_out;
  uint32_t n = (uint32_t)in_sizes[0];   // 8192*4096 = 33554432
  dim3 block(256);
  dim3 grid((n + 255u) / 256u);
  BernoulliSampling_kernel<<<grid, block, 0, stream>>>(z, out, n);
}

// Round 9
// 731.897 us; speedup vs baseline: 1.0082x; 1.0082x over previous
//
#include <hip/hip_runtime.h>
#include <stdint.h>

// BernoulliSampling: out[pos] = mean_{s<10}( U[s,pos] < sigmoid(z[pos]) )
// Verified bit-exact vs JAX reference (round 7: absmax = 0.0):
//   U = threefry2x32 partitionable layout, key (0,42), bits(i) = o0^o1 of
//   threefry(x0=0, x1=i), i = s*n + pos;  u < p  <=>  (bits>>9) < ceil(p*2^23).
// Round-8 change: force v_alignbit_b32 rotates (counters implied ~1480
// VALU lane-ops/elem => compiler was emitting 3-op rotates) + hoist the
// per-sample >>9 into the threshold: (bits>>9) < t  <=>  bits <= (t<<9)-1
// (exact for t >= 1; t = ceil(sigmoid(z)*2^23) >= 1 for all finite z with
// p > 0 — input is standard normal, |z| < 7, so t in [1, 2^23), and the
// t = 2^23 wrap case is also exact).

#define NS 10u

__device__ __forceinline__ uint32_t rotl32(uint32_t x, uint32_t r) {
  // v_alignbit_b32 D = ((u64(S0:S1)) >> S2)[31:0]; alignbit(x,x,s) = rotr(x,s)
  return __builtin_amdgcn_alignbit(x, x, 32u - r);
}

__device__ __forceinline__ void tf_round(uint32_t& x0, uint32_t& x1, uint32_t r) {
  x0 += x1;
  x1 = rotl32(x1, r);
  x1 ^= x0;
}

// threefry2x32 with key (k0=0, k1=42):
//   ks0=0, ks1=42, ks2=0x1BD11BDA^0^42=0x1BD11BF0; specialized for c0==0.
__device__ __forceinline__ uint32_t threefry_0_42_fold(uint32_t c1) {
  uint32_t x0 = 0u;               // c0 + ks0
  uint32_t x1 = c1 + 42u;         // c1 + ks1
  tf_round(x0, x1, 13); tf_round(x0, x1, 15); tf_round(x0, x1, 26); tf_round(x0, x1, 6);
  x0 += 42u;           x1 += 0x1BD11BF0u + 1u;   // +ks1, +ks2+1
  tf_round(x0, x1, 17); tf_round(x0, x1, 29); tf_round(x0, x1, 16); tf_round(x0, x1, 24);
  x0 += 0x1BD11BF0u;   x1 += 0u + 2u;            // +ks2, +ks0+2
  tf_round(x0, x1, 13); tf_round(x0, x1, 15); tf_round(x0, x1, 26); tf_round(x0, x1, 6);
  x0 += 0u;            x1 += 42u + 3u;           // +ks0, +ks1+3
  tf_round(x0, x1, 17); tf_round(x0, x1, 29); tf_round(x0, x1, 16); tf_round(x0, x1, 24);
  x0 += 42u;           x1 += 0x1BD11BF0u + 4u;   // +ks1, +ks2+4
  tf_round(x0, x1, 13); tf_round(x0, x1, 15); tf_round(x0, x1, 26); tf_round(x0, x1, 6);
  x0 += 0x1BD11BF0u;   x1 += 0u + 5u;            // +ks2, +ks0+5
  return x0 ^ x1;                 // 32-bit partitionable fold
}

__global__ __launch_bounds__(256) void BernoulliSampling_kernel(
    const float* __restrict__ z, float* __restrict__ out, uint32_t n) {
  uint32_t pos = blockIdx.x * 256u + threadIdx.x;
  if (pos >= n) return;

  float zv = z[pos];
  // XLA LogisticExpander: sigmoid(x) = 1 / (1 + exp(-x)); expf == __ocml_exp_f32
  float p = 1.0f / (1.0f + expf(-zv));

  uint32_t t = (uint32_t)ceilf(p * 8388608.0f);   // ceil(p * 2^23), exact
  uint32_t tm1 = (t << 9) - 1u;   // (bits>>9) < t  <=>  bits <= tm1  (t >= 1)

  uint32_t cnt = 0;
#pragma unroll
  for (uint32_t s = 0; s < NS; ++s) {
    uint32_t bits = threefry_0_42_fold(s * n + pos);
    cnt += (bits <= tm1) ? 1u : 0u;   // v_cmp_le_u32 + v_addc
  }

  out[pos] = (float)cnt * 0.1f;       // == cnt/10 within 1 ulp (<< tolerance)
}

extern "C" void kernel_launch(void* const* d_in, const int* in_sizes, int n_in,
                              void* d_out, int out_size, void* d_ws, size_t ws_size,
                              hipStream_t stream) {
  const float* z = (const float*)d_in[0];
  float* out = (float*)d_out;
  uint32_t n = (uint32_t)in_sizes[0];   // 8192*4096 = 33554432
  dim3 block(256);
  dim3 grid((n + 255u) / 256u);
  BernoulliSampling_kernel<<<grid, block, 0, stream>>>(z, out, n);
}

// Round 10
// 719.613 us; speedup vs baseline: 1.0254x; 1.0171x over previous
//
#include <hip/hip_runtime.h>
#include <stdint.h>

// BernoulliSampling: out[pos] = mean_{s<10}( U[s,pos] < sigmoid(z[pos]) )
// Bit-exact vs JAX (round 7/9: absmax = 0.0): threefry2x32 partitionable,
// key (0,42), bits(i) = o0^o1 of threefry(x0=0, x1=i), i = s*n+pos;
// u < p  <=>  bits <= (ceil(p*2^23)<<9)-1  (exact, t>=1 for finite z).
//
// Round-10 change: chain-major -> ROUND-MAJOR threefry. Round 9 showed
// VGPR=8 => compiler serialized the 10 chains into one long dependent ALU
// chain per thread; measured 64.3 lanes/cy/CU = half the SIMD-32 ceiling
// despite "VALUBusy 98%" (gfx94x-formula, likely 2x inflated). Keeping all
// 10 chains live (X0[10],X1[10], statically indexed, fully unrolled) forces
// 10-way ILP in the instruction stream. ~26 VGPR, still max occupancy.

#define NS 10

__device__ __forceinline__ uint32_t rotl32(uint32_t x, uint32_t r) {
  return __builtin_amdgcn_alignbit(x, x, 32u - r);   // rotr(32-r) == rotl(r)
}

// One threefry round applied to all NS chains (round-major).
#define TF_ROUND(rr)                                        \
  _Pragma("unroll")                                         \
  for (int s = 0; s < NS; ++s) {                            \
    X0[s] += X1[s];                                         \
    X1[s] = rotl32(X1[s], (rr));                            \
    X1[s] ^= X0[s];                                         \
  }

// Key-schedule injection on all chains (adds of 0 are folded by compiler).
#define TF_INJ(a0, a1)                                      \
  _Pragma("unroll")                                         \
  for (int s = 0; s < NS; ++s) {                            \
    X0[s] += (a0);                                          \
    X1[s] += (a1);                                          \
  }

__global__ __launch_bounds__(256) void BernoulliSampling_kernel(
    const float* __restrict__ z, float* __restrict__ out, uint32_t n) {
  uint32_t pos = blockIdx.x * 256u + threadIdx.x;
  if (pos >= n) return;

  float zv = z[pos];
  // XLA LogisticExpander: sigmoid = 1/(1+exp(-x)); expf == __ocml_exp_f32
  float p = 1.0f / (1.0f + expf(-zv));
  uint32_t t = (uint32_t)ceilf(p * 8388608.0f);   // ceil(p*2^23), exact
  uint32_t tm1 = (t << 9) - 1u;                   // bits <= tm1  <=>  (bits>>9) < t

  // threefry2x32, key (0,42): ks0=0, ks1=42, ks2=0x1BD11BF0. c0=0 for all.
  uint32_t X0[NS], X1[NS];
#pragma unroll
  for (int s = 0; s < NS; ++s) {
    X0[s] = 0u;                                   // c0 + ks0
    X1[s] = (uint32_t)s * n + pos + 42u;          // c1 + ks1 (s*n folds to SGPR)
  }

  TF_ROUND(13) TF_ROUND(15) TF_ROUND(26) TF_ROUND(6)
  TF_INJ(42u, 0x1BD11BF0u + 1u)                   // +ks1, +ks2+1
  TF_ROUND(17) TF_ROUND(29) TF_ROUND(16) TF_ROUND(24)
  TF_INJ(0x1BD11BF0u, 0u + 2u)                    // +ks2, +ks0+2
  TF_ROUND(13) TF_ROUND(15) TF_ROUND(26) TF_ROUND(6)
  TF_INJ(0u, 42u + 3u)                            // +ks0, +ks1+3
  TF_ROUND(17) TF_ROUND(29) TF_ROUND(16) TF_ROUND(24)
  TF_INJ(42u, 0x1BD11BF0u + 4u)                   // +ks1, +ks2+4
  TF_ROUND(13) TF_ROUND(15) TF_ROUND(26) TF_ROUND(6)
  TF_INJ(0x1BD11BF0u, 0u + 5u)                    // +ks2, +ks0+5

  uint32_t cnt = 0;
#pragma unroll
  for (int s = 0; s < NS; ++s) {
    uint32_t bits = X0[s] ^ X1[s];                // partitionable 32-bit fold
    cnt += (bits <= tm1) ? 1u : 0u;
  }

  out[pos] = (float)cnt * 0.1f;                   // == cnt/10 within 1 ulp
}

extern "C" void kernel_launch(void* const* d_in, const int* in_sizes, int n_in,
                              void* d_out, int out_size, void* d_ws, size_t ws_size,
                              hipStream_t stream) {
  const float* z = (const float*)d_in[0];
  float* out = (float*)d_out;
  uint32_t n = (uint32_t)in_sizes[0];   // 8192*4096 = 33554432
  dim3 block(256);
  dim3 grid((n + 255u) / 256u);
  BernoulliSampling_kernel<<<grid, block, 0, stream>>>(z, out, n);
}